// Round 10
// baseline (247.756 us; speedup 1.0000x reference)
//
#include <hip/hip_runtime.h>
#include <hip/hip_fp16.h>
#include <stdint.h>

#define DIN 128
#define DHID 128
#define DOUT2 64
#define NGRP 8  // atomic privatization ways

typedef __attribute__((ext_vector_type(8))) short short8v;  // 8 bf16 (4 VGPRs)
typedef __attribute__((ext_vector_type(4))) float f32x4;    // MFMA acc

__device__ __forceinline__ unsigned short f2bf(float f) {
    unsigned u = __float_as_uint(f);
    u += 0x7fffu + ((u >> 16) & 1u);
    return (unsigned short)(u >> 16);
}
__device__ __forceinline__ float bf2f(unsigned short b) {
    return __uint_as_float(((unsigned)b) << 16);
}
__device__ __forceinline__ float bflo(unsigned v) { return __uint_as_float(v << 16); }
__device__ __forceinline__ float bfhi(unsigned v) { return __uint_as_float(v & 0xffff0000u); }
__device__ __forceinline__ unsigned short f2h(float f) {
    return __half_as_ushort(__float2half_rn(f));
}
__device__ __forceinline__ float h2f(unsigned bits) {
    return __half2float(__ushort_as_half((unsigned short)bits));
}

// per-wave int64-vs-int32 detect (int64 edge_index -> zero hi-words at odd u32 slots)
__device__ __forceinline__ int detect_mode(const unsigned* ei) {
    int lane = threadIdx.x & 63;
    unsigned hi = ei[2 * lane + 1];
    return (__ballot(hi == 0u) == ~0ull) ? 1 : 0;
}

// ---------------- prep: Wt transposes (blocks 0,1) + privatized degree histogram ----------
// Group g MUST be a function of edge index e (g = (e>>8)&7), identical in prep and
// scatter — R8 bug: deriving g from raw blockIdx (offset by 2 here) mismatched the
// scatter's grouping and corrupted the CSR segments.
__global__ void prep_kernel(const float* __restrict__ W1, const float* __restrict__ W2,
                            unsigned short* __restrict__ wt1, unsigned short* __restrict__ wt2,
                            const int* ei32, const long long* ei64, unsigned* deg8, int E) {
    if (blockIdx.x == 0) {
        // coalesced wt writes; strided W1 reads (64 KB, L2-resident)
        for (int idx = threadIdx.x; idx < 128 * 128; idx += 256) {
            int n = idx >> 7, k = idx & 127;
            wt1[idx] = f2bf(W1[k * 128 + n]);
        }
    } else if (blockIdx.x == 1) {
        for (int idx = threadIdx.x; idx < 64 * 128; idx += 256) {
            int n = idx >> 7, k = idx & 127;
            wt2[idx] = f2bf(W2[k * 64 + n]);
        }
    } else {
        int mode = detect_mode((const unsigned*)ei32);
        int bi = blockIdx.x - 2;
        int g = bi & (NGRP - 1);  // == (e>>8)&7, matches scatter
        int e = bi * 256 + threadIdx.x;
        if (e < E) {
            int d = mode ? (int)ei64[(size_t)E + e] : ei32[(size_t)E + e];
            atomicAdd(&deg8[(size_t)d * NGRP + g], 1u);
        }
    }
}

// ---------------- MFMA bf16 GEMM: out_bf16[M x DO] = A[M x 128] @ Wt^T ----------------
template <int DO, typename AT>
__global__ __launch_bounds__(256) void gemm_mfma_kernel(const AT* __restrict__ A,
                                                        const unsigned short* __restrict__ Wt,
                                                        unsigned short* __restrict__ out,
                                                        int M) {
    constexpr int NT = DO / 16;  // n-tiles
    __shared__ unsigned short As[64 * 136];
    const int tid = threadIdx.x;
    const int row0 = blockIdx.x * 64;

    if constexpr (sizeof(AT) == 4) {
        for (int idx = tid; idx < 64 * 32; idx += 256) {
            int r = idx >> 5, c4 = idx & 31;
            int row = row0 + r;
            ushort4 o = {0, 0, 0, 0};
            if (row < M) {
                float4 v = ((const float4*)A)[(size_t)row * 32 + c4];
                o.x = f2bf(v.x);
                o.y = f2bf(v.y);
                o.z = f2bf(v.z);
                o.w = f2bf(v.w);
            }
            *(ushort4*)&As[r * 136 + c4 * 4] = o;
        }
    } else {
        for (int idx = tid; idx < 64 * 16; idx += 256) {
            int r = idx >> 4, c8 = idx & 15;
            int row = row0 + r;
            uint4 v = {0u, 0u, 0u, 0u};
            if (row < M) v = ((const uint4*)A)[(size_t)row * 16 + c8];
            *(uint4*)&As[r * 136 + c8 * 8] = v;
        }
    }
    __syncthreads();

    const int wid = tid >> 6, lane = tid & 63;
    const int r16 = lane & 15, g = lane >> 4;
    f32x4 acc[NT];
#pragma unroll
    for (int n = 0; n < NT; n++) acc[n] = (f32x4){0.f, 0.f, 0.f, 0.f};

    const unsigned short* a_base = &As[(wid * 16 + r16) * 136 + g * 8];
    const unsigned short* b_base = Wt + r16 * 128 + g * 8;
#pragma unroll
    for (int kk = 0; kk < 4; kk++) {
        short8v a = *(const short8v*)(a_base + kk * 32);
#pragma unroll
        for (int n = 0; n < NT; n++) {
            short8v b = *(const short8v*)(b_base + n * 16 * 128 + kk * 32);
            acc[n] = __builtin_amdgcn_mfma_f32_16x16x32_bf16(a, b, acc[n], 0, 0, 0);
        }
    }

    const int rbase = row0 + wid * 16 + g * 4;
#pragma unroll
    for (int n = 0; n < NT; n++) {
#pragma unroll
        for (int q = 0; q < 4; q++) {
            int row = rbase + q;
            if (row < M) out[(size_t)row * DO + n * 16 + r16] = f2bf(acc[n][q]);
        }
    }
}

// ---------------- scan over deg8 (M8 = N*8 words); thread t owns node's 8 counts ----------
__global__ __launch_bounds__(256) void scan_blocksum_kernel(const unsigned* deg8, int* bsum,
                                                            float* dinv, int N) {
    __shared__ int s[256];
    int t = threadIdx.x;
    int node = blockIdx.x * 256 + t;
    int sum = 0;
    if (node < N) {
        const int4* p = (const int4*)(deg8 + (size_t)node * NGRP);
        int4 a = p[0], b = p[1];
        sum = a.x + a.y + a.z + a.w + b.x + b.y + b.z + b.w;
        dinv[node] = rsqrtf((float)(sum + 1));
    }
    s[t] = sum;
    __syncthreads();
    for (int off = 128; off > 0; off >>= 1) {
        if (t < off) s[t] += s[t + off];
        __syncthreads();
    }
    if (t == 0) bsum[blockIdx.x] = s[0];
}

// exclusive scan of block sums (nb <= 256), write total to rowp8[M8]
__global__ __launch_bounds__(256) void scan_bsum_kernel(int* bsum, int* rowp8, int nb, int M8) {
    __shared__ int s[256];
    int t = threadIdx.x;
    int v = (t < nb) ? bsum[t] : 0;
    s[t] = v;
    __syncthreads();
    for (int off = 1; off < 256; off <<= 1) {
        int u = (t >= off) ? s[t - off] : 0;
        __syncthreads();
        s[t] += u;
        __syncthreads();
    }
    if (t < nb) bsum[t] = s[t] - v;  // exclusive
    if (t == 255) rowp8[M8] = s[255];
}

__global__ __launch_bounds__(256) void scan_write_kernel(const unsigned* deg8, const int* bsum,
                                                         int* rowp8, int* curs8, int N) {
    __shared__ int s[256];
    int t = threadIdx.x;
    int node = blockIdx.x * 256 + t;
    int d8[8];
    int sum = 0;
    if (node < N) {
        const int4* p = (const int4*)(deg8 + (size_t)node * NGRP);
        int4 a = p[0], b = p[1];
        d8[0] = a.x; d8[1] = a.y; d8[2] = a.z; d8[3] = a.w;
        d8[4] = b.x; d8[5] = b.y; d8[6] = b.z; d8[7] = b.w;
#pragma unroll
        for (int j = 0; j < 8; j++) sum += d8[j];
    } else {
#pragma unroll
        for (int j = 0; j < 8; j++) d8[j] = 0;
    }
    s[t] = sum;
    __syncthreads();
    for (int off = 1; off < 256; off <<= 1) {
        int u = (t >= off) ? s[t - off] : 0;
        __syncthreads();
        s[t] += u;
        __syncthreads();
    }
    int run = bsum[blockIdx.x] + s[t] - sum;
    if (node < N) {
        size_t base = (size_t)node * NGRP;
#pragma unroll
        for (int j = 0; j < 8; j++) {
            rowp8[base + j] = run;
            curs8[base + j] = run;
            run += d8[j];
        }
    }
}

// ---------------- scatter edges into packed CSR (privatized cursors) ----------------
__global__ void scatter_pack32_kernel(const int* ei32, const long long* ei64, const float* dinv,
                                      int* curs8, unsigned* csr, int E) {
    int mode = detect_mode((const unsigned*)ei32);
    int g = blockIdx.x & (NGRP - 1);  // == (e>>8)&7, matches prep
    int e = blockIdx.x * blockDim.x + threadIdx.x;
    if (e >= E) return;
    int s, d;
    if (mode) {
        s = (int)ei64[e];
        d = (int)ei64[(size_t)E + e];
    } else {
        s = ei32[e];
        d = ei32[(size_t)E + e];
    }
    int pos = atomicAdd(&curs8[(size_t)d * NGRP + g], 1);
    csr[pos] = (unsigned)s | ((unsigned)f2h(dinv[s]) << 16);
}

__global__ void scatter_pack64_kernel(const int* ei32, const long long* ei64, const float* dinv,
                                      int* curs8, unsigned long long* csr, int E) {
    int mode = detect_mode((const unsigned*)ei32);
    int g = blockIdx.x & (NGRP - 1);
    int e = blockIdx.x * blockDim.x + threadIdx.x;
    if (e >= E) return;
    int s, d;
    if (mode) {
        s = (int)ei64[e];
        d = (int)ei64[(size_t)E + e];
    } else {
        s = ei32[e];
        d = ei32[(size_t)E + e];
    }
    int pos = atomicAdd(&curs8[(size_t)d * NGRP + g], 1);
    csr[pos] = (unsigned long long)(unsigned)s |
               ((unsigned long long)__float_as_uint(dinv[s]) << 32);
}

__device__ __forceinline__ void unpack(unsigned p, int& s, float& w) {
    s = (int)(p & 0xffffu);
    w = h2f(p >> 16);
}
__device__ __forceinline__ void unpack(unsigned long long p, int& s, float& w) {
    s = (int)(unsigned)(p & 0xffffffffu);
    w = __uint_as_float((unsigned)(p >> 32));
}

// ---------------- CSR aggregation: wave-per-node, unroll 8, fp32 accumulate ----------
// row i occupies csr[rowp8[i*8] .. rowp8[i*8+8])  (contiguous across the 8 groups)
template <int D, bool RELU, typename OT, typename CT>
__global__ __launch_bounds__(256) void agg_kernel(const unsigned short* __restrict__ h,
                                                  const CT* __restrict__ csr,
                                                  const int* __restrict__ rowp8,
                                                  const float* __restrict__ dinv,
                                                  const float* __restrict__ bias,
                                                  OT* __restrict__ out, int N) {
    const int wid = threadIdx.x >> 6;
    const int lane = threadIdx.x & 63;
    const int i = blockIdx.x * 4 + wid;
    if (i >= N) return;
    const float di = dinv[i];
    const int start = rowp8[(size_t)i * NGRP], end = rowp8[(size_t)i * NGRP + NGRP];

    if constexpr (D == 128) {
        const unsigned* hu = (const unsigned*)h;
        unsigned sv = hu[(size_t)i * 64 + lane];
        float a0 = di * bflo(sv), b0 = di * bfhi(sv);  // self loop
        float a1 = 0.f, b1 = 0.f, a2 = 0.f, b2 = 0.f, a3 = 0.f, b3 = 0.f;
        int j = start;
        for (; j + 8 <= end; j += 8) {
            int s[8];
            float w[8];
            unsigned v[8];
#pragma unroll
            for (int u = 0; u < 8; u++) unpack(csr[j + u], s[u], w[u]);
#pragma unroll
            for (int u = 0; u < 8; u++) v[u] = hu[(size_t)s[u] * 64 + lane];
            a0 = fmaf(w[0], bflo(v[0]), a0);
            b0 = fmaf(w[0], bfhi(v[0]), b0);
            a1 = fmaf(w[1], bflo(v[1]), a1);
            b1 = fmaf(w[1], bfhi(v[1]), b1);
            a2 = fmaf(w[2], bflo(v[2]), a2);
            b2 = fmaf(w[2], bfhi(v[2]), b2);
            a3 = fmaf(w[3], bflo(v[3]), a3);
            b3 = fmaf(w[3], bfhi(v[3]), b3);
            a0 = fmaf(w[4], bflo(v[4]), a0);
            b0 = fmaf(w[4], bfhi(v[4]), b0);
            a1 = fmaf(w[5], bflo(v[5]), a1);
            b1 = fmaf(w[5], bfhi(v[5]), b1);
            a2 = fmaf(w[6], bflo(v[6]), a2);
            b2 = fmaf(w[6], bfhi(v[6]), b2);
            a3 = fmaf(w[7], bflo(v[7]), a3);
            b3 = fmaf(w[7], bfhi(v[7]), b3);
        }
        for (; j < end; ++j) {
            int s0;
            float w0;
            unpack(csr[j], s0, w0);
            unsigned v0 = hu[(size_t)s0 * 64 + lane];
            a0 = fmaf(w0, bflo(v0), a0);
            b0 = fmaf(w0, bfhi(v0), b0);
        }
        float2 bv = ((const float2*)bias)[lane];
        float rx = di * ((a0 + a1) + (a2 + a3)) + bv.x;
        float ry = di * ((b0 + b1) + (b2 + b3)) + bv.y;
        if (RELU) {
            rx = fmaxf(rx, 0.f);
            ry = fmaxf(ry, 0.f);
        }
        if constexpr (sizeof(OT) == 2) {
            unsigned pv = (unsigned)f2bf(rx) | ((unsigned)f2bf(ry) << 16);
            ((unsigned*)out)[(size_t)i * 64 + lane] = pv;
        } else {
            ((float2*)out)[(size_t)i * 64 + lane] = make_float2(rx, ry);
        }
    } else {  // D == 64
        float a0 = di * bf2f(h[(size_t)i * 64 + lane]);  // self loop
        float a1 = 0.f, a2 = 0.f, a3 = 0.f;
        int j = start;
        for (; j + 8 <= end; j += 8) {
            int s[8];
            float w[8];
            float v[8];
#pragma unroll
            for (int u = 0; u < 8; u++) unpack(csr[j + u], s[u], w[u]);
#pragma unroll
            for (int u = 0; u < 8; u++) v[u] = bf2f(h[(size_t)s[u] * 64 + lane]);
            a0 = fmaf(w[0], v[0], a0);
            a1 = fmaf(w[1], v[1], a1);
            a2 = fmaf(w[2], v[2], a2);
            a3 = fmaf(w[3], v[3], a3);
            a0 = fmaf(w[4], v[4], a0);
            a1 = fmaf(w[5], v[5], a1);
            a2 = fmaf(w[6], v[6], a2);
            a3 = fmaf(w[7], v[7], a3);
        }
        for (; j < end; ++j) {
            int s0;
            float w0;
            unpack(csr[j], s0, w0);
            a0 = fmaf(w0, bf2f(h[(size_t)s0 * 64 + lane]), a0);
        }
        float r = di * ((a0 + a1) + (a2 + a3)) + bias[lane];
        if (RELU) r = fmaxf(r, 0.f);
        if constexpr (sizeof(OT) == 2) {
            out[(size_t)i * 64 + lane] = (OT)f2bf(r);
        } else {
            out[(size_t)i * 64 + lane] = r;
        }
    }
}

extern "C" void kernel_launch(void* const* d_in, const int* in_sizes, int n_in,
                              void* d_out, int out_size, void* d_ws, size_t ws_size,
                              hipStream_t stream) {
    const float* x  = (const float*)d_in[0];
    const void*  ei = d_in[1];
    const float* W1 = (const float*)d_in[2];
    const float* b1 = (const float*)d_in[3];
    const float* W2 = (const float*)d_in[4];
    const float* b2 = (const float*)d_in[5];
    float* out = (float*)d_out;

    const int N = in_sizes[0] / DIN;
    const int E = in_sizes[1] / 2;
    const int M8 = N * NGRP;

    char* ws = (char*)d_ws;
    size_t off = 0;
    auto alloc = [&](size_t bytes) -> void* {
        void* p = ws + off;
        off += (bytes + 255) & ~(size_t)255;
        return p;
    };
    unsigned*       deg8  = (unsigned*)alloc((size_t)M8 * 4);
    float*          dinv  = (float*)alloc((size_t)N * 4);
    int*            rowp8 = (int*)alloc((size_t)(M8 + 1) * 4);
    int*            curs8 = (int*)alloc((size_t)M8 * 4);
    int*            bsum  = (int*)alloc(1024 * 4);
    unsigned short* wt1   = (unsigned short*)alloc(128 * 128 * 2);
    unsigned short* wt2   = (unsigned short*)alloc(128 * 64 * 2);
    void*           csr   = alloc((size_t)E * 8);  // 4B used when N<=65535
    unsigned short* h1    = (unsigned short*)alloc((size_t)N * DHID * 2);  // bf16
    unsigned short* o1    = (unsigned short*)alloc((size_t)N * DHID * 2);  // bf16
    unsigned short* h2    = h1;  // h1 dead after agg1; reuse

    const int nb = (N + 255) / 256;  // scan blocks (256 nodes x 8 words each); must be <= 256
    const int gemmBlocks = (N + 63) / 64;
    const int degBlocks = (E + 255) / 256;

    hipMemsetAsync(deg8, 0, (size_t)M8 * 4, stream);
    prep_kernel<<<2 + degBlocks, 256, 0, stream>>>(W1, W2, wt1, wt2, (const int*)ei,
                                                   (const long long*)ei, deg8, E);
    gemm_mfma_kernel<DHID, float><<<gemmBlocks, 256, 0, stream>>>(x, wt1, h1, N);
    scan_blocksum_kernel<<<nb, 256, 0, stream>>>(deg8, bsum, dinv, N);
    scan_bsum_kernel<<<1, 256, 0, stream>>>(bsum, rowp8, nb, M8);
    scan_write_kernel<<<nb, 256, 0, stream>>>(deg8, bsum, rowp8, curs8, N);

    if (N <= 65535) {
        unsigned* csr32 = (unsigned*)csr;
        scatter_pack32_kernel<<<degBlocks, 256, 0, stream>>>((const int*)ei,
                                                             (const long long*)ei, dinv, curs8,
                                                             csr32, E);
        agg_kernel<DHID, true, unsigned short, unsigned><<<(N + 3) / 4, 256, 0, stream>>>(
            h1, csr32, rowp8, dinv, b1, o1, N);
        gemm_mfma_kernel<DOUT2, unsigned short><<<gemmBlocks, 256, 0, stream>>>(o1, wt2, h2, N);
        agg_kernel<DOUT2, false, float, unsigned><<<(N + 3) / 4, 256, 0, stream>>>(
            h2, csr32, rowp8, dinv, b2, out, N);
    } else {
        unsigned long long* csr64 = (unsigned long long*)csr;
        scatter_pack64_kernel<<<degBlocks, 256, 0, stream>>>((const int*)ei,
                                                             (const long long*)ei, dinv, curs8,
                                                             csr64, E);
        agg_kernel<DHID, true, unsigned short, unsigned long long><<<(N + 3) / 4, 256, 0,
                                                                     stream>>>(h1, csr64, rowp8,
                                                                               dinv, b1, o1, N);
        gemm_mfma_kernel<DOUT2, unsigned short><<<gemmBlocks, 256, 0, stream>>>(o1, wt2, h2, N);
        agg_kernel<DOUT2, false, float, unsigned long long><<<(N + 3) / 4, 256, 0, stream>>>(
            h2, csr64, rowp8, dinv, b2, out, N);
    }
}